// Round 10
// baseline (2548.686 us; speedup 1.0000x reference)
//
#include <hip/hip_runtime.h>
#include <math.h>

#define ROWS 32
#define NTHREADS 256
#define TAU 2e-4f

typedef float f32x4 __attribute__((ext_vector_type(4)));
typedef short s16x8 __attribute__((ext_vector_type(8)));

// d_ws layout (bytes): fragment-ordered bf16-split weights.
// For matrix W[K][N]: tile tl = n16*(K/32) + s covers cols n16*16..+16, k s*32..+32.
// Element [k = s*32 + ks*8 + j][n = n16*16 + lr] stored at (tl*64 + ks*16+lr)*8 + j (shorts)
// -> a wave's B-frag load is ONE coalesced 1KB read: base + lane*16B.
#define WS_WIN_HI (0)
#define WS_WIN_LO (512*1024)
#define WS_W1_HI  (1024*1024)
#define WS_W1_LO  (WS_W1_HI + 128*1024)
#define WS_W2_HI  (WS_W1_HI + 256*1024)
#define WS_W2_LO  (WS_W2_HI + 64*1024)
#define WS_WO_HI  (WS_W2_HI + 128*1024)
#define WS_WO_LO  (WS_WO_HI + 16*1024)

__device__ __forceinline__ unsigned short f2bh(float f) {
    union { float f; unsigned u; } v; v.f = f;
    unsigned r = v.u + 0x7fffu + ((v.u >> 16) & 1u);   // RNE bf16
    return (unsigned short)(r >> 16);
}
__device__ __forceinline__ float bh2f(unsigned short h) {
    union { unsigned u; float f; } v; v.u = ((unsigned)h) << 16;
    return v.f;
}
__device__ __forceinline__ unsigned packsplit(float f) {
    unsigned short h = f2bh(f);
    unsigned short l = f2bh(f - bh2f(h));
    return (unsigned)h | ((unsigned)l << 16);
}

// ---------------- prep: W[k][n] fp32 -> fragment-ordered hi/lo bf16 ----------
__global__ __launch_bounds__(256)
void prep_frag(const float* __restrict__ W_in, const float* __restrict__ W1,
               const float* __restrict__ W2,   const float* __restrict__ Wo,
               void* ws)
{
    const int t    = threadIdx.x;
    const int tg   = blockIdx.x * 4 + (t >> 6);
    const int lane = t & 63;
    const float* src; int N, Kt, tl; size_t offh, offl;
    if (tg < 512)      { src = W_in; N = 256; Kt = 32; tl = tg;       offh = WS_WIN_HI; offl = WS_WIN_LO; }
    else if (tg < 640) { src = W1;   N = 256; Kt = 8;  tl = tg - 512; offh = WS_W1_HI;  offl = WS_W1_LO; }
    else if (tg < 704) { src = W2;   N = 128; Kt = 8;  tl = tg - 640; offh = WS_W2_HI;  offl = WS_W2_LO; }
    else               { src = Wo;   N = 64;  Kt = 4;  tl = tg - 704; offh = WS_WO_HI;  offl = WS_WO_LO; }
    const int n16 = tl / Kt, s = tl % Kt;
    const int lr = lane & 15, ks = lane >> 4;
    const int n  = n16 * 16 + lr;
    const int kb = s * 32 + ks * 8;
    s16x8 hv, lv;
    #pragma unroll
    for (int j = 0; j < 8; ++j) {
        const float f = src[(size_t)(kb + j) * N + n];
        const unsigned short h = f2bh(f);
        hv[j] = (short)h;
        lv[j] = (short)f2bh(f - bh2f(h));
    }
    const size_t base = ((size_t)tl * 64 + lane) * 8;
    *reinterpret_cast<s16x8*>((short*)((char*)ws + offh) + base) = hv;
    *reinterpret_cast<s16x8*>((short*)((char*)ws + offl) + base) = lv;
}

// ---------------- main fused kernel ----------------
// LDS 34.4 KB -> 4 blocks/CU. lgt (32x64 fp32) overlays ap[r][192..255].
struct alignas(16) SMem {
    union {
        unsigned ap[32][260];   // packed (bf16 hi | lo<<16) activations [row][col]
        struct { double a1d[256]; double h2d[128]; double lgd[64]; } rs;
    } u;
    float2 lnbuf[32][4];        // per-row (sum,sumsq) per wave-quarter
    double rred[8];
};

#define MFMA(a, b, c) __builtin_amdgcn_mfma_f32_16x16x32_bf16((a), (b), (c), 0, 0, 0)

#define UNPACK2(P0, P1, AH, AL) do {                                          \
    const unsigned _w[8] = {P0.x, P0.y, P0.z, P0.w, P1.x, P1.y, P1.z, P1.w};  \
    _Pragma("unroll")                                                         \
    for (int _j = 0; _j < 8; ++_j) {                                          \
        AH[_j] = (short)(_w[_j] & 0xffff);                                    \
        AL[_j] = (short)(_w[_j] >> 16);                                       \
    }                                                                         \
} while (0)

__global__ __launch_bounds__(NTHREADS, 4)
void gating_mfma(const float* __restrict__ x,
                 const float* __restrict__ W_in, const float* __restrict__ b_in,
                 const float* __restrict__ ln1_g, const float* __restrict__ ln1_b,
                 const float* __restrict__ W1,   const float* __restrict__ b1,
                 const float* __restrict__ ln2_g, const float* __restrict__ ln2_b,
                 const float* __restrict__ W2,   const float* __restrict__ b2,
                 const float* __restrict__ Wo,   const float* __restrict__ bo,
                 const float* __restrict__ temp,
                 const void* __restrict__ ws,
                 float* __restrict__ out)
{
    __shared__ SMem sm;
    __shared__ unsigned cmask;
    const int tid  = threadIdx.x;
    const int lane = tid & 63;
    const int nq   = tid >> 6;        // wave = n-quarter (64 cols), all 32 rows
    const int lr   = lane & 15;       // frag row (A) / col (B,C)
    const int ks   = lane >> 4;       // k-slot; C/D row = ks*4+j
    const int row_base = blockIdx.x * ROWS;
    if (tid == 0) cmask = 0;

    float* out_topp = out;
    float* out_topi = out + (size_t)65536 * 8;
    float* out_gp   = out + (size_t)65536 * 16;
    float* lgtf = reinterpret_cast<float*>(&sm.u.ap[0][0]);   // lgt(r,c)=lgtf[r*260+192+c]

    const short* whin_h = (const short*)((const char*)ws + WS_WIN_HI);
    const short* whin_l = (const short*)((const char*)ws + WS_WIN_LO);
    const short* w1_h   = (const short*)((const char*)ws + WS_W1_HI);
    const short* w1_l   = (const short*)((const char*)ws + WS_W1_LO);
    const short* w2_h   = (const short*)((const char*)ws + WS_W2_HI);
    const short* w2_l   = (const short*)((const char*)ws + WS_W2_LO);
    const short* wo_h   = (const short*)((const char*)ws + WS_WO_HI);
    const short* wo_l   = (const short*)((const char*)ws + WS_WO_LO);

    // ================= GEMM1: h0 = relu(x @ W_in + b_in) =================
    f32x4 hacc[2][4];
    #pragma unroll
    for (int mt = 0; mt < 2; ++mt)
        #pragma unroll
        for (int gq = 0; gq < 4; ++gq) hacc[mt][gq] = (f32x4)0.f;

    const float* xr0 = x + (size_t)(row_base + lr) * 1024 + ks * 8;
    const float* xr1 = xr0 + (size_t)16 * 1024;
    float4 c00 = *reinterpret_cast<const float4*>(xr0);
    float4 c01 = *reinterpret_cast<const float4*>(xr0 + 4);
    float4 c10 = *reinterpret_cast<const float4*>(xr1);
    float4 c11 = *reinterpret_cast<const float4*>(xr1 + 4);

    for (int s = 0; s < 32; ++s) {
        // batched B loads (8 in flight; latency hidden under split VALU + other waves)
        s16x8 bh[4], bl[4];
        #pragma unroll
        for (int gq = 0; gq < 4; ++gq) {
            const size_t tb = (((size_t)(nq * 4 + gq) * 32 + s) * 64 + lane) * 8;
            bh[gq] = *reinterpret_cast<const s16x8*>(whin_h + tb);
            bl[gq] = *reinterpret_cast<const s16x8*>(whin_l + tb);
        }
        // split A for both m-tiles (trunc split; residual < 2^-16 |x|)
        s16x8 ah[2], al[2];
        {
            const float xa0[8] = {c00.x, c00.y, c00.z, c00.w, c01.x, c01.y, c01.z, c01.w};
            const float xa1[8] = {c10.x, c10.y, c10.z, c10.w, c11.x, c11.y, c11.z, c11.w};
            #pragma unroll
            for (int j = 0; j < 8; ++j) {
                const unsigned u0 = __float_as_uint(xa0[j]);
                ah[0][j] = (short)(u0 >> 16);
                al[0][j] = (short)(__float_as_uint(xa0[j] - __uint_as_float(u0 & 0xffff0000u)) >> 16);
                const unsigned u1 = __float_as_uint(xa1[j]);
                ah[1][j] = (short)(u1 >> 16);
                al[1][j] = (short)(__float_as_uint(xa1[j] - __uint_as_float(u1 & 0xffff0000u)) >> 16);
            }
        }
        if (s < 31) {
            c00 = *reinterpret_cast<const float4*>(xr0 + (s + 1) * 32);
            c01 = *reinterpret_cast<const float4*>(xr0 + (s + 1) * 32 + 4);
            c10 = *reinterpret_cast<const float4*>(xr1 + (s + 1) * 32);
            c11 = *reinterpret_cast<const float4*>(xr1 + (s + 1) * 32 + 4);
        }
        #pragma unroll
        for (int mt = 0; mt < 2; ++mt)
            #pragma unroll
            for (int gq = 0; gq < 4; ++gq) {
                hacc[mt][gq] = MFMA(ah[mt], bh[gq], hacc[mt][gq]);
                hacc[mt][gq] = MFMA(al[mt], bh[gq], hacc[mt][gq]);
                hacc[mt][gq] = MFMA(ah[mt], bl[gq], hacc[mt][gq]);
            }
    }
    #pragma unroll
    for (int mt = 0; mt < 2; ++mt)
        #pragma unroll
        for (int gq = 0; gq < 4; ++gq) {
            const float bi = b_in[nq * 64 + gq * 16 + lr];
            #pragma unroll
            for (int j = 0; j < 4; ++j) hacc[mt][gq][j] = fmaxf(hacc[mt][gq][j] + bi, 0.f);
        }

    // ===== LN1 -> relu -> packed ap =====
    {
        float sj[2][4], qj[2][4];
        #pragma unroll
        for (int mt = 0; mt < 2; ++mt)
            #pragma unroll
            for (int j = 0; j < 4; ++j) {
                float s = 0.f, q = 0.f;
                #pragma unroll
                for (int gq = 0; gq < 4; ++gq) { s += hacc[mt][gq][j]; q += hacc[mt][gq][j] * hacc[mt][gq][j]; }
                sj[mt][j] = s; qj[mt][j] = q;
            }
        #pragma unroll
        for (int m = 1; m < 16; m <<= 1)
            #pragma unroll
            for (int mt = 0; mt < 2; ++mt)
                #pragma unroll
                for (int j = 0; j < 4; ++j) {
                    sj[mt][j] += __shfl_xor(sj[mt][j], m);
                    qj[mt][j] += __shfl_xor(qj[mt][j], m);
                }
        if (lr == 0) {
            #pragma unroll
            for (int mt = 0; mt < 2; ++mt)
                #pragma unroll
                for (int j = 0; j < 4; ++j)
                    sm.lnbuf[mt * 16 + ks * 4 + j][nq] = make_float2(sj[mt][j], qj[mt][j]);
        }
        __syncthreads();
        float mu[2][4], rsv[2][4];
        #pragma unroll
        for (int mt = 0; mt < 2; ++mt)
            #pragma unroll
            for (int j = 0; j < 4; ++j) {
                const float2* lb = sm.lnbuf[mt * 16 + ks * 4 + j];
                const float ss = (lb[0].x + lb[1].x) + (lb[2].x + lb[3].x);
                const float qq = (lb[0].y + lb[1].y) + (lb[2].y + lb[3].y);
                mu[mt][j]  = ss * (1.f / 256.f);
                rsv[mt][j] = rsqrtf(qq * (1.f / 256.f) - mu[mt][j] * mu[mt][j] + 1e-5f);
            }
        #pragma unroll
        for (int mt = 0; mt < 2; ++mt)
            #pragma unroll
            for (int gq = 0; gq < 4; ++gq) {
                const int n = nq * 64 + gq * 16 + lr;
                const float gg = ln1_g[n], bb = ln1_b[n];
                #pragma unroll
                for (int j = 0; j < 4; ++j) {
                    const float v = fmaxf((hacc[mt][gq][j] - mu[mt][j]) * rsv[mt][j] * gg + bb, 0.f);
                    sm.u.ap[mt * 16 + ks * 4 + j][n] = packsplit(v);
                }
            }
    }
    __syncthreads();

    // ================= GEMM2: h1 = a1 @ W1 + b1 + h0 =================
    {
        f32x4 acc2[2][4];
        #pragma unroll
        for (int mt = 0; mt < 2; ++mt)
            #pragma unroll
            for (int gq = 0; gq < 4; ++gq) acc2[mt][gq] = (f32x4)0.f;
        for (int s = 0; s < 8; ++s) {
            const int kof = s * 32 + ks * 8;
            const uint4 p0 = *reinterpret_cast<const uint4*>(&sm.u.ap[lr][kof]);
            const uint4 p1 = *reinterpret_cast<const uint4*>(&sm.u.ap[lr][kof + 4]);
            const uint4 p2 = *reinterpret_cast<const uint4*>(&sm.u.ap[16 + lr][kof]);
            const uint4 p3 = *reinterpret_cast<const uint4*>(&sm.u.ap[16 + lr][kof + 4]);
            s16x8 ah[2], al[2];
            UNPACK2(p0, p1, ah[0], al[0]);
            UNPACK2(p2, p3, ah[1], al[1]);
            #pragma unroll
            for (int sp = 0; sp < 2; ++sp) {   // half-batches keep VGPR <= 128
                s16x8 bh[2], bl[2];
                #pragma unroll
                for (int g2 = 0; g2 < 2; ++g2) {
                    const size_t tb = (((size_t)(nq * 4 + sp * 2 + g2) * 8 + s) * 64 + lane) * 8;
                    bh[g2] = *reinterpret_cast<const s16x8*>(w1_h + tb);
                    bl[g2] = *reinterpret_cast<const s16x8*>(w1_l + tb);
                }
                #pragma unroll
                for (int mt = 0; mt < 2; ++mt)
                    #pragma unroll
                    for (int g2 = 0; g2 < 2; ++g2) {
                        const int gq = sp * 2 + g2;
                        acc2[mt][gq] = MFMA(ah[mt], bh[g2], acc2[mt][gq]);
                        acc2[mt][gq] = MFMA(al[mt], bh[g2], acc2[mt][gq]);
                        acc2[mt][gq] = MFMA(ah[mt], bl[g2], acc2[mt][gq]);
                    }
            }
        }
        #pragma unroll
        for (int mt = 0; mt < 2; ++mt)
            #pragma unroll
            for (int gq = 0; gq < 4; ++gq) {
                const float bv = b1[nq * 64 + gq * 16 + lr];
                #pragma unroll
                for (int j = 0; j < 4; ++j)
                    hacc[mt][gq][j] = acc2[mt][gq][j] + bv + hacc[mt][gq][j];   // hacc := h1
            }
    }
    __syncthreads();   // a1 reads done before ap rewrite

    // ===== LN2 -> relu -> packed ap =====
    {
        float sj[2][4], qj[2][4];
        #pragma unroll
        for (int mt = 0; mt < 2; ++mt)
            #pragma unroll
            for (int j = 0; j < 4; ++j) {
                float s = 0.f, q = 0.f;
                #pragma unroll
                for (int gq = 0; gq < 4; ++gq) { s += hacc[mt][gq][j]; q += hacc[mt][gq][j] * hacc[mt][gq][j]; }
                sj[mt][j] = s; qj[mt][j] = q;
            }
        #pragma unroll
        for (int m = 1; m < 16; m <<= 1)
            #pragma unroll
            for (int mt = 0; mt < 2; ++mt)
                #pragma unroll
                for (int j = 0; j < 4; ++j) {
                    sj[mt][j] += __shfl_xor(sj[mt][j], m);
                    qj[mt][j] += __shfl_xor(qj[mt][j], m);
                }
        if (lr == 0) {
            #pragma unroll
            for (int mt = 0; mt < 2; ++mt)
                #pragma unroll
                for (int j = 0; j < 4; ++j)
                    sm.lnbuf[mt * 16 + ks * 4 + j][nq] = make_float2(sj[mt][j], qj[mt][j]);
        }
        __syncthreads();
        float mu[2][4], rsv[2][4];
        #pragma unroll
        for (int mt = 0; mt < 2; ++mt)
            #pragma unroll
            for (int j = 0; j < 4; ++j) {
                const float2* lb = sm.lnbuf[mt * 16 + ks * 4 + j];
                const float ss = (lb[0].x + lb[1].x) + (lb[2].x + lb[3].x);
                const float qq = (lb[0].y + lb[1].y) + (lb[2].y + lb[3].y);
                mu[mt][j]  = ss * (1.f / 256.f);
                rsv[mt][j] = rsqrtf(qq * (1.f / 256.f) - mu[mt][j] * mu[mt][j] + 1e-5f);
            }
        #pragma unroll
        for (int mt = 0; mt < 2; ++mt)
            #pragma unroll
            for (int gq = 0; gq < 4; ++gq) {
                const int n = nq * 64 + gq * 16 + lr;
                const float gg = ln2_g[n], bb = ln2_b[n];
                #pragma unroll
                for (int j = 0; j < 4; ++j) {
                    const float v = fmaxf((hacc[mt][gq][j] - mu[mt][j]) * rsv[mt][j] * gg + bb, 0.f);
                    sm.u.ap[mt * 16 + ks * 4 + j][n] = packsplit(v);
                }
            }
    }
    __syncthreads();

    // ================= GEMM3: h2 = a2 @ W2 + b2 ([32,128]) =================
    {
        f32x4 acc3[2][2];
        #pragma unroll
        for (int mt = 0; mt < 2; ++mt)
            #pragma unroll
            for (int g2 = 0; g2 < 2; ++g2) acc3[mt][g2] = (f32x4)0.f;
        for (int s = 0; s < 8; ++s) {
            const int kof = s * 32 + ks * 8;
            const uint4 p0 = *reinterpret_cast<const uint4*>(&sm.u.ap[lr][kof]);
            const uint4 p1 = *reinterpret_cast<const uint4*>(&sm.u.ap[lr][kof + 4]);
            const uint4 p2 = *reinterpret_cast<const uint4*>(&sm.u.ap[16 + lr][kof]);
            const uint4 p3 = *reinterpret_cast<const uint4*>(&sm.u.ap[16 + lr][kof + 4]);
            s16x8 ah[2], al[2];
            UNPACK2(p0, p1, ah[0], al[0]);
            UNPACK2(p2, p3, ah[1], al[1]);
            s16x8 bh[2], bl[2];
            #pragma unroll
            for (int g2 = 0; g2 < 2; ++g2) {
                const size_t tb = (((size_t)(nq * 2 + g2) * 8 + s) * 64 + lane) * 8;
                bh[g2] = *reinterpret_cast<const s16x8*>(w2_h + tb);
                bl[g2] = *reinterpret_cast<const s16x8*>(w2_l + tb);
            }
            #pragma unroll
            for (int mt = 0; mt < 2; ++mt)
                #pragma unroll
                for (int g2 = 0; g2 < 2; ++g2) {
                    acc3[mt][g2] = MFMA(ah[mt], bh[g2], acc3[mt][g2]);
                    acc3[mt][g2] = MFMA(al[mt], bh[g2], acc3[mt][g2]);
                    acc3[mt][g2] = MFMA(ah[mt], bl[g2], acc3[mt][g2]);
                }
        }
        __syncthreads();   // a2 reads done before ap rewrite (h2)
        #pragma unroll
        for (int mt = 0; mt < 2; ++mt)
            #pragma unroll
            for (int g2 = 0; g2 < 2; ++g2) {
                const int n = nq * 32 + g2 * 16 + lr;
                const float bv = b2[n];
                #pragma unroll
                for (int j = 0; j < 4; ++j)
                    sm.u.ap[mt * 16 + ks * 4 + j][n] = packsplit(acc3[mt][g2][j] + bv);
            }
    }
    __syncthreads();

    // ================= GEMM4: logits = (h2 @ W_out + b_out)/T =================
    {
        f32x4 acc4[2];
        acc4[0] = (f32x4)0.f; acc4[1] = (f32x4)0.f;
        for (int s = 0; s < 4; ++s) {
            const int kof = s * 32 + ks * 8;
            const uint4 p0 = *reinterpret_cast<const uint4*>(&sm.u.ap[lr][kof]);
            const uint4 p1 = *reinterpret_cast<const uint4*>(&sm.u.ap[lr][kof + 4]);
            const uint4 p2 = *reinterpret_cast<const uint4*>(&sm.u.ap[16 + lr][kof]);
            const uint4 p3 = *reinterpret_cast<const uint4*>(&sm.u.ap[16 + lr][kof + 4]);
            s16x8 ah[2], al[2];
            UNPACK2(p0, p1, ah[0], al[0]);
            UNPACK2(p2, p3, ah[1], al[1]);
            const size_t tb = (((size_t)(nq * 4 + s)) * 64 + lane) * 8;
            const s16x8 bh = *reinterpret_cast<const s16x8*>(wo_h + tb);
            const s16x8 bl = *reinterpret_cast<const s16x8*>(wo_l + tb);
            #pragma unroll
            for (int mt = 0; mt < 2; ++mt) {
                acc4[mt] = MFMA(ah[mt], bh, acc4[mt]);
                acc4[mt] = MFMA(al[mt], bh, acc4[mt]);
                acc4[mt] = MFMA(ah[mt], bl, acc4[mt]);
            }
        }
        const float T = temp[0];
        const int n = nq * 16 + lr;
        const float bv = bo[n];
        #pragma unroll
        for (int mt = 0; mt < 2; ++mt)
            #pragma unroll
            for (int j = 0; j < 4; ++j)
                lgtf[(size_t)(mt * 16 + ks * 4 + j) * 260 + 192 + n] = (acc4[mt][j] + bv) / T;
    }
    __syncthreads();

    // ============ softmax + top-8 + contested detection ============
    {
        const float tau = TAU / temp[0];
        for (int j = 0; j < 8; ++j) {
            const int r = nq * 8 + j;
            const float v = lgtf[(size_t)r * 260 + 192 + lane];
            float m = v;
            #pragma unroll
            for (int mk = 32; mk >= 1; mk >>= 1) m = fmaxf(m, __shfl_xor(m, mk));
            float p = expf(v - m);
            float ssum = p;
            #pragma unroll
            for (int mk = 32; mk >= 1; mk >>= 1) ssum += __shfl_xor(ssum, mk);
            const float gp = p / ssum;
            out_gp[(size_t)(row_base + r) * 64 + lane] = gp;

            float pv = v;
            int   pi = lane;
            float sum8 = 0.f, myv = 0.f, prev = 0.f;
            int   myi = 0;
            bool  contested = false;
            #pragma unroll
            for (int t = 0; t < 9; ++t) {
                float cv = pv;
                int   ci = pi;
                #pragma unroll
                for (int mk = 32; mk >= 1; mk >>= 1) {
                    const float ov = __shfl_xor(cv, mk);
                    const int   oi = __shfl_xor(ci, mk);
                    if (ov > cv || (ov == cv && oi < ci)) { cv = ov; ci = oi; }
                }
                if (t > 0 && (prev - cv) < tau) contested = true;
                prev = cv;
                if (t < 8) {
                    const float g = __shfl(gp, ci);
                    sum8 += g;
                    if (lane == t)  { myv = g; myi = ci; }
                    if (lane == ci) pv = -3.0e38f;
                }
            }
            if (lane < 8) {
                out_topp[(size_t)(row_base + r) * 8 + lane] = myv / sum8;
                out_topi[(size_t)(row_base + r) * 8 + lane] = (float)myi;
            }
            if (lane == 0 && contested) atomicOr(&cmask, 1u << r);
        }
    }

    // ============ fp64 rescue of contested rows (block-parallel) ============
    __syncthreads();
    unsigned cm = cmask;   // uniform across block
    while (cm) {
        const int r = __ffs(cm) - 1;
        cm &= cm - 1;
        const float* xr = x + (size_t)(row_base + r) * 1024;
        const int c = tid;
        const int wvv = tid >> 6;

        double a0 = 0.0, a1 = 0.0, a2 = 0.0, a3 = 0.0;
        for (int k = 0; k < 1024; k += 4) {
            a0 = fma((double)xr[k + 0], (double)W_in[(size_t)(k + 0) * 256 + c], a0);
            a1 = fma((double)xr[k + 1], (double)W_in[(size_t)(k + 1) * 256 + c], a1);
            a2 = fma((double)xr[k + 2], (double)W_in[(size_t)(k + 2) * 256 + c], a2);
            a3 = fma((double)xr[k + 3], (double)W_in[(size_t)(k + 3) * 256 + c], a3);
        }
        const double h0 = fmax((a0 + a1) + (a2 + a3) + (double)b_in[c], 0.0);

        double s = h0, q = h0 * h0;
        #pragma unroll
        for (int m = 1; m < 64; m <<= 1) { s += __shfl_xor(s, m); q += __shfl_xor(q, m); }
        if (lane == 0) { sm.rred[wvv * 2] = s; sm.rred[wvv * 2 + 1] = q; }
        __syncthreads();
        {
            const double ss = (sm.rred[0] + sm.rred[2]) + (sm.rred[4] + sm.rred[6]);
            const double qq = (sm.rred[1] + sm.rred[3]) + (sm.rred[5] + sm.rred[7]);
            const double mu = ss * (1.0 / 256.0);
            const double rsv = 1.0 / sqrt(qq * (1.0 / 256.0) - mu * mu + 1e-5);
            sm.u.rs.a1d[c] = fmax((h0 - mu) * rsv * (double)ln1_g[c] + (double)ln1_b[c], 0.0);
        }
        __syncthreads();

        double b0 = 0.0, b1c = 0.0, b2c = 0.0, b3c = 0.0;
        for (int k = 0; k < 256; k += 4) {
            b0  = fma(sm.u.rs.a1d[k + 0], (double)W1[(size_t)(k + 0) * 256 + c], b0);
            b1c = fma(sm.u.rs.a1d[k + 1], (double)W1[(size_t)(k + 1) * 256 + c], b1c);
            b2c = fma(sm.u.rs.a1d[k + 2], (double)W1[(size_t)(k + 2) * 256 + c], b2c);
            b3c = fma(sm.u.rs.a1d[k + 3], (double)W1[(size_t)(k + 3) * 256 + c], b3c);
        }
        const double h1 = (b0 + b1c) + (b2c + b3c) + (double)b1[c] + h0;

        s = h1; q = h1 * h1;
        #pragma unroll
        for (int m = 1; m < 64; m <<= 1) { s += __shfl_xor(s, m); q += __shfl_xor(q, m); }
        if (lane == 0) { sm.rred[wvv * 2] = s; sm.rred[wvv * 2 + 1] = q; }
        __syncthreads();   // also orders stage-2 a1d reads before rewrite
        {
            const double ss = (sm.rred[0] + sm.rred[2]) + (sm.rred[4] + sm.rred[6]);
            const double qq = (sm.rred[1] + sm.rred[3]) + (sm.rred[5] + sm.rred[7]);
            const double mu = ss * (1.0 / 256.0);
            const double rsv = 1.0 / sqrt(qq * (1.0 / 256.0) - mu * mu + 1e-5);
            sm.u.rs.a1d[c] = fmax((h1 - mu) * rsv * (double)ln2_g[c] + (double)ln2_b[c], 0.0);
        }
        __syncthreads();

        if (c < 128) {
            double d0 = 0.0, d1 = 0.0, d2 = 0.0, d3 = 0.0;
            for (int k = 0; k < 256; k += 4) {
                d0 = fma(sm.u.rs.a1d[k + 0], (double)W2[(size_t)(k + 0) * 128 + c], d0);
                d1 = fma(sm.u.rs.a1d[k + 1], (double)W2[(size_t)(k + 1) * 128 + c], d1);
                d2 = fma(sm.u.rs.a1d[k + 2], (double)W2[(size_t)(k + 2) * 128 + c], d2);
                d3 = fma(sm.u.rs.a1d[k + 3], (double)W2[(size_t)(k + 3) * 128 + c], d3);
            }
            sm.u.rs.h2d[c] = (d0 + d1) + (d2 + d3) + (double)b2[c];
        }
        __syncthreads();

        if (c < 64) {
            double e0 = 0.0, e1 = 0.0;
            for (int k = 0; k < 128; k += 2) {
                e0 = fma(sm.u.rs.h2d[k + 0], (double)Wo[(size_t)(k + 0) * 64 + c], e0);
                e1 = fma(sm.u.rs.h2d[k + 1], (double)Wo[(size_t)(k + 1) * 64 + c], e1);
            }
            sm.u.rs.lgd[c] = (e0 + e1 + (double)bo[c]) / (double)temp[0];
        }
        __syncthreads();

        if (tid < 64) {
            const int ln = tid;
            const double v = sm.u.rs.lgd[ln];
            double m = v;
            #pragma unroll
            for (int mk = 32; mk >= 1; mk >>= 1) m = fmax(m, __shfl_xor(m, mk));
            const double p = exp(v - m);
            double ssum = p;
            #pragma unroll
            for (int mk = 32; mk >= 1; mk >>= 1) ssum += __shfl_xor(ssum, mk);
            const double gp = p / ssum;
            out_gp[(size_t)(row_base + r) * 64 + ln] = (float)gp;

            double pv = gp;
            int    pi = ln;
            double sum8 = 0.0, myv = 0.0;
            int    myi = 0;
            #pragma unroll
            for (int t = 0; t < 8; ++t) {
                double cv = pv;
                int    ci = pi;
                #pragma unroll
                for (int mk = 32; mk >= 1; mk >>= 1) {
                    const double ov = __shfl_xor(cv, mk);
                    const int    oi = __shfl_xor(ci, mk);
                    if (ov > cv || (ov == cv && oi < ci)) { cv = ov; ci = oi; }
                }
                sum8 += cv;
                if (ln == t)  { myv = cv; myi = ci; }
                if (ln == ci) pv = -1.0;
            }
            if (ln < 8) {
                out_topp[(size_t)(row_base + r) * 8 + ln] = (float)(myv / sum8);
                out_topi[(size_t)(row_base + r) * 8 + ln] = (float)myi;
            }
        }
        __syncthreads();
    }
}

extern "C" void kernel_launch(void* const* d_in, const int* in_sizes, int n_in,
                              void* d_out, int out_size, void* d_ws, size_t ws_size,
                              hipStream_t stream) {
    const float* x     = (const float*)d_in[0];
    const float* W_in  = (const float*)d_in[1];
    const float* b_in  = (const float*)d_in[2];
    const float* ln1_g = (const float*)d_in[3];
    const float* ln1_b = (const float*)d_in[4];
    const float* W1    = (const float*)d_in[5];
    const float* b1    = (const float*)d_in[6];
    const float* ln2_g = (const float*)d_in[7];
    const float* ln2_b = (const float*)d_in[8];
    const float* W2    = (const float*)d_in[9];
    const float* b2    = (const float*)d_in[10];
    const float* Wo    = (const float*)d_in[11];
    const float* bo    = (const float*)d_in[12];
    const float* temp  = (const float*)d_in[13];

    prep_frag<<<dim3(180), dim3(256), 0, stream>>>(W_in, W1, W2, Wo, d_ws);
    gating_mfma<<<dim3(65536 / ROWS), dim3(NTHREADS), 0, stream>>>(
        x, W_in, b_in, ln1_g, ln1_b, W1, b1, ln2_g, ln2_b, W2, b2, Wo, bo, temp,
        d_ws, (float*)d_out);
}

// Round 11
// 735.053 us; speedup vs baseline: 3.4674x; 3.4674x over previous
//
#include <hip/hip_runtime.h>
#include <math.h>

#define ROWS 32
#define NTHREADS 256
#define TAU 2.5e-5f

typedef float f32x4 __attribute__((ext_vector_type(4)));
typedef short s16x8 __attribute__((ext_vector_type(8)));

// d_ws layout (bytes): fragment-ordered bf16-split weights.
// For matrix W[K][N]: tile tl = n16*(K/32) + s covers cols n16*16..+16, k s*32..+32.
// Element [k = s*32 + ks*8 + j][n = n16*16 + lr] stored at (tl*64 + ks*16+lr)*8 + j (shorts)
// -> a wave's B-frag load is ONE coalesced 1KB read: base + lane*16B.
#define WS_WIN_HI (0)
#define WS_WIN_LO (512*1024)
#define WS_W1_HI  (1024*1024)
#define WS_W1_LO  (WS_W1_HI + 128*1024)
#define WS_W2_HI  (WS_W1_HI + 256*1024)
#define WS_W2_LO  (WS_W2_HI + 64*1024)
#define WS_WO_HI  (WS_W2_HI + 128*1024)
#define WS_WO_LO  (WS_WO_HI + 16*1024)

__device__ __forceinline__ unsigned short f2bh(float f) {
    union { float f; unsigned u; } v; v.f = f;
    unsigned r = v.u + 0x7fffu + ((v.u >> 16) & 1u);   // RNE bf16
    return (unsigned short)(r >> 16);
}
__device__ __forceinline__ float bh2f(unsigned short h) {
    union { unsigned u; float f; } v; v.u = ((unsigned)h) << 16;
    return v.f;
}
__device__ __forceinline__ unsigned packsplit(float f) {
    unsigned short h = f2bh(f);
    unsigned short l = f2bh(f - bh2f(h));
    return (unsigned)h | ((unsigned)l << 16);
}

// ---------------- prep: W[k][n] fp32 -> fragment-ordered hi/lo bf16 ----------
__global__ __launch_bounds__(256)
void prep_frag(const float* __restrict__ W_in, const float* __restrict__ W1,
               const float* __restrict__ W2,   const float* __restrict__ Wo,
               void* ws)
{
    const int t    = threadIdx.x;
    const int tg   = blockIdx.x * 4 + (t >> 6);
    const int lane = t & 63;
    const float* src; int N, Kt, tl; size_t offh, offl;
    if (tg < 512)      { src = W_in; N = 256; Kt = 32; tl = tg;       offh = WS_WIN_HI; offl = WS_WIN_LO; }
    else if (tg < 640) { src = W1;   N = 256; Kt = 8;  tl = tg - 512; offh = WS_W1_HI;  offl = WS_W1_LO; }
    else if (tg < 704) { src = W2;   N = 128; Kt = 8;  tl = tg - 640; offh = WS_W2_HI;  offl = WS_W2_LO; }
    else               { src = Wo;   N = 64;  Kt = 4;  tl = tg - 704; offh = WS_WO_HI;  offl = WS_WO_LO; }
    const int n16 = tl / Kt, s = tl % Kt;
    const int lr = lane & 15, ks = lane >> 4;
    const int n  = n16 * 16 + lr;
    const int kb = s * 32 + ks * 8;
    s16x8 hv, lv;
    #pragma unroll
    for (int j = 0; j < 8; ++j) {
        const float f = src[(size_t)(kb + j) * N + n];
        const unsigned short h = f2bh(f);
        hv[j] = (short)h;
        lv[j] = (short)f2bh(f - bh2f(h));
    }
    const size_t base = ((size_t)tl * 64 + lane) * 8;
    *reinterpret_cast<s16x8*>((short*)((char*)ws + offh) + base) = hv;
    *reinterpret_cast<s16x8*>((short*)((char*)ws + offl) + base) = lv;
}

// ---------------- main fused kernel ----------------
struct alignas(16) SMem {
    union {
        unsigned ap[32][260];   // packed (bf16 hi | lo<<16) activations, [row][col]
        struct { double a1d[256]; double h2d[128]; double lgd[64]; } rs;
    } u;
    float  lgt[32][68];
    float2 lnbuf[2][16][2];     // [m-tile][row][n-half] = (sum, sumsq)
    double rred[8];             // rescue LN cross-wave reduce
};

#define MFMA(a, b, c) __builtin_amdgcn_mfma_f32_16x16x32_bf16((a), (b), (c), 0, 0, 0)

__global__ __launch_bounds__(NTHREADS, 3)
void gating_mfma(const float* __restrict__ x,
                 const float* __restrict__ W_in, const float* __restrict__ b_in,
                 const float* __restrict__ ln1_g, const float* __restrict__ ln1_b,
                 const float* __restrict__ W1,   const float* __restrict__ b1,
                 const float* __restrict__ ln2_g, const float* __restrict__ ln2_b,
                 const float* __restrict__ W2,   const float* __restrict__ b2,
                 const float* __restrict__ Wo,   const float* __restrict__ bo,
                 const float* __restrict__ temp,
                 const void* __restrict__ ws,
                 float* __restrict__ out)
{
    __shared__ SMem sm;
    __shared__ unsigned cmask;
    const int tid  = threadIdx.x;
    const int lane = tid & 63;
    const int wv   = tid >> 6;        // 0..3
    const int mt   = wv & 1;          // m-tile (rows mt*16..+16)
    const int nh   = wv >> 1;         // n-half
    const int lr   = lane & 15;       // frag row/col
    const int ks   = lane >> 4;       // k-slot (0..3)
    const int row_base = blockIdx.x * ROWS;
    if (tid == 0) cmask = 0;

    float* out_topp = out;
    float* out_topi = out + (size_t)65536 * 8;
    float* out_gp   = out + (size_t)65536 * 16;

    const short* whin_h = (const short*)((const char*)ws + WS_WIN_HI);
    const short* whin_l = (const short*)((const char*)ws + WS_WIN_LO);
    const short* w1_h   = (const short*)((const char*)ws + WS_W1_HI);
    const short* w1_l   = (const short*)((const char*)ws + WS_W1_LO);
    const short* w2_h   = (const short*)((const char*)ws + WS_W2_HI);
    const short* w2_l   = (const short*)((const char*)ws + WS_W2_LO);
    const short* wo_h   = (const short*)((const char*)ws + WS_WO_HI);
    const short* wo_l   = (const short*)((const char*)ws + WS_WO_LO);

    // ================= GEMM1: h0 = relu(x @ W_in + b_in) =================
    f32x4 hacc[8];
    #pragma unroll
    for (int g = 0; g < 8; ++g) hacc[g] = (f32x4)0.f;

    const float* xrow = x + (size_t)(row_base + mt * 16 + lr) * 1024 + ks * 8;
    float4 cf0 = *reinterpret_cast<const float4*>(xrow);
    float4 cf1 = *reinterpret_cast<const float4*>(xrow + 4);
    for (int s = 0; s < 32; ++s) {
        float4 nf0, nf1;
        if (s < 31) {
            nf0 = *reinterpret_cast<const float4*>(xrow + (s + 1) * 32);
            nf1 = *reinterpret_cast<const float4*>(xrow + (s + 1) * 32 + 4);
        }
        const float xa[8] = {cf0.x, cf0.y, cf0.z, cf0.w, cf1.x, cf1.y, cf1.z, cf1.w};
        s16x8 ah, al;   // cheap trunc split: residual still < 2^-16 |x|
        #pragma unroll
        for (int j = 0; j < 8; ++j) {
            const unsigned u = __float_as_uint(xa[j]);
            ah[j] = (short)(u >> 16);
            const float r = xa[j] - __uint_as_float(u & 0xffff0000u);
            al[j] = (short)(__float_as_uint(r) >> 16);
        }
        #pragma unroll
        for (int g = 0; g < 8; ++g) {
            const size_t tb = (((size_t)(nh * 8 + g) * 32 + s) * 64 + lane) * 8;
            const s16x8 bh = *reinterpret_cast<const s16x8*>(whin_h + tb);
            const s16x8 bl = *reinterpret_cast<const s16x8*>(whin_l + tb);
            hacc[g] = MFMA(ah, bh, hacc[g]);
            hacc[g] = MFMA(al, bh, hacc[g]);
            hacc[g] = MFMA(ah, bl, hacc[g]);
        }
        cf0 = nf0; cf1 = nf1;
    }
    #pragma unroll
    for (int g = 0; g < 8; ++g) {
        const int n = nh * 128 + g * 16 + lr;
        const float bi = b_in[n];
        #pragma unroll
        for (int j = 0; j < 4; ++j) hacc[g][j] = fmaxf(hacc[g][j] + bi, 0.f);
    }

    // ===== LN1 -> relu -> packed a_t =====
    {
        float s4[4] = {0, 0, 0, 0}, q4[4] = {0, 0, 0, 0};
        #pragma unroll
        for (int g = 0; g < 8; ++g)
            #pragma unroll
            for (int j = 0; j < 4; ++j) { s4[j] += hacc[g][j]; q4[j] += hacc[g][j] * hacc[g][j]; }
        #pragma unroll
        for (int m = 1; m < 16; m <<= 1) {
            #pragma unroll
            for (int j = 0; j < 4; ++j) {
                s4[j] += __shfl_xor(s4[j], m);
                q4[j] += __shfl_xor(q4[j], m);
            }
        }
        if (lr == 0) {
            #pragma unroll
            for (int j = 0; j < 4; ++j)
                sm.lnbuf[mt][ks * 4 + j][nh] = make_float2(s4[j], q4[j]);
        }
        __syncthreads();
        float mu[4], rsv[4];
        #pragma unroll
        for (int j = 0; j < 4; ++j) {
            const float2 c0 = sm.lnbuf[mt][ks * 4 + j][0];
            const float2 c1 = sm.lnbuf[mt][ks * 4 + j][1];
            const float ss = c0.x + c1.x, qq = c0.y + c1.y;
            mu[j] = ss * (1.f / 256.f);
            rsv[j] = rsqrtf(qq * (1.f / 256.f) - mu[j] * mu[j] + 1e-5f);
        }
        #pragma unroll
        for (int g = 0; g < 8; ++g) {
            const int n = nh * 128 + g * 16 + lr;
            const float gg = ln1_g[n], bb = ln1_b[n];
            #pragma unroll
            for (int j = 0; j < 4; ++j) {
                const float v = fmaxf((hacc[g][j] - mu[j]) * rsv[j] * gg + bb, 0.f);
                sm.u.ap[mt * 16 + ks * 4 + j][n] = packsplit(v);
            }
        }
    }
    __syncthreads();

    // ================= GEMM2: h1 = a1 @ W1 + b1 + h0 =================
    {
        f32x4 acc2[8];
        #pragma unroll
        for (int g = 0; g < 8; ++g) acc2[g] = (f32x4)0.f;
        for (int s = 0; s < 8; ++s) {
            const int kof = s * 32 + ks * 8;
            const uint4 q0 = *reinterpret_cast<const uint4*>(&sm.u.ap[mt * 16 + lr][kof]);
            const uint4 q1 = *reinterpret_cast<const uint4*>(&sm.u.ap[mt * 16 + lr][kof + 4]);
            const unsigned uu[8] = {q0.x, q0.y, q0.z, q0.w, q1.x, q1.y, q1.z, q1.w};
            s16x8 ah, al;
            #pragma unroll
            for (int j = 0; j < 8; ++j) { ah[j] = (short)(uu[j] & 0xffff); al[j] = (short)(uu[j] >> 16); }
            #pragma unroll
            for (int g = 0; g < 8; ++g) {
                const size_t tb = (((size_t)(nh * 8 + g) * 8 + s) * 64 + lane) * 8;
                const s16x8 bh = *reinterpret_cast<const s16x8*>(w1_h + tb);
                const s16x8 bl = *reinterpret_cast<const s16x8*>(w1_l + tb);
                acc2[g] = MFMA(ah, bh, acc2[g]);
                acc2[g] = MFMA(al, bh, acc2[g]);
                acc2[g] = MFMA(ah, bl, acc2[g]);
            }
        }
        #pragma unroll
        for (int g = 0; g < 8; ++g) {
            const int n = nh * 128 + g * 16 + lr;
            const float bv = b1[n];
            #pragma unroll
            for (int j = 0; j < 4; ++j) hacc[g][j] = acc2[g][j] + bv + hacc[g][j];  // hacc := h1
        }
    }
    __syncthreads();   // all a1 reads done before ap rewrite

    // ===== LN2 -> relu -> packed a_t =====
    {
        float s4[4] = {0, 0, 0, 0}, q4[4] = {0, 0, 0, 0};
        #pragma unroll
        for (int g = 0; g < 8; ++g)
            #pragma unroll
            for (int j = 0; j < 4; ++j) { s4[j] += hacc[g][j]; q4[j] += hacc[g][j] * hacc[g][j]; }
        #pragma unroll
        for (int m = 1; m < 16; m <<= 1) {
            #pragma unroll
            for (int j = 0; j < 4; ++j) {
                s4[j] += __shfl_xor(s4[j], m);
                q4[j] += __shfl_xor(q4[j], m);
            }
        }
        if (lr == 0) {
            #pragma unroll
            for (int j = 0; j < 4; ++j)
                sm.lnbuf[mt][ks * 4 + j][nh] = make_float2(s4[j], q4[j]);
        }
        __syncthreads();
        float mu[4], rsv[4];
        #pragma unroll
        for (int j = 0; j < 4; ++j) {
            const float2 c0 = sm.lnbuf[mt][ks * 4 + j][0];
            const float2 c1 = sm.lnbuf[mt][ks * 4 + j][1];
            const float ss = c0.x + c1.x, qq = c0.y + c1.y;
            mu[j] = ss * (1.f / 256.f);
            rsv[j] = rsqrtf(qq * (1.f / 256.f) - mu[j] * mu[j] + 1e-5f);
        }
        #pragma unroll
        for (int g = 0; g < 8; ++g) {
            const int n = nh * 128 + g * 16 + lr;
            const float gg = ln2_g[n], bb = ln2_b[n];
            #pragma unroll
            for (int j = 0; j < 4; ++j) {
                const float v = fmaxf((hacc[g][j] - mu[j]) * rsv[j] * gg + bb, 0.f);
                sm.u.ap[mt * 16 + ks * 4 + j][n] = packsplit(v);
            }
        }
    }
    __syncthreads();

    // ================= GEMM3: h2 = a2 @ W2 + b2 ([32,128]) =================
    {
        f32x4 acc3[4];
        #pragma unroll
        for (int g = 0; g < 4; ++g) acc3[g] = (f32x4)0.f;
        for (int s = 0; s < 8; ++s) {
            const int kof = s * 32 + ks * 8;
            const uint4 q0 = *reinterpret_cast<const uint4*>(&sm.u.ap[mt * 16 + lr][kof]);
            const uint4 q1 = *reinterpret_cast<const uint4*>(&sm.u.ap[mt * 16 + lr][kof + 4]);
            const unsigned uu[8] = {q0.x, q0.y, q0.z, q0.w, q1.x, q1.y, q1.z, q1.w};
            s16x8 ah, al;
            #pragma unroll
            for (int j = 0; j < 8; ++j) { ah[j] = (short)(uu[j] & 0xffff); al[j] = (short)(uu[j] >> 16); }
            #pragma unroll
            for (int g = 0; g < 4; ++g) {
                const size_t tb = (((size_t)(nh * 4 + g) * 8 + s) * 64 + lane) * 8;
                const s16x8 bh = *reinterpret_cast<const s16x8*>(w2_h + tb);
                const s16x8 bl = *reinterpret_cast<const s16x8*>(w2_l + tb);
                acc3[g] = MFMA(ah, bh, acc3[g]);
                acc3[g] = MFMA(al, bh, acc3[g]);
                acc3[g] = MFMA(ah, bl, acc3[g]);
            }
        }
        __syncthreads();   // a2 reads done before ap rewrite (h2)
        #pragma unroll
        for (int g = 0; g < 4; ++g) {
            const int n = nh * 64 + g * 16 + lr;
            const float bv = b2[n];
            #pragma unroll
            for (int j = 0; j < 4; ++j)
                sm.u.ap[mt * 16 + ks * 4 + j][n] = packsplit(acc3[g][j] + bv);
        }
    }
    __syncthreads();

    // ================= GEMM4: logits = (h2 @ W_out + b_out)/T =================
    {
        f32x4 acc4[2];
        acc4[0] = (f32x4)0.f; acc4[1] = (f32x4)0.f;
        for (int s = 0; s < 4; ++s) {
            const int kof = s * 32 + ks * 8;
            const uint4 q0 = *reinterpret_cast<const uint4*>(&sm.u.ap[mt * 16 + lr][kof]);
            const uint4 q1 = *reinterpret_cast<const uint4*>(&sm.u.ap[mt * 16 + lr][kof + 4]);
            const unsigned uu[8] = {q0.x, q0.y, q0.z, q0.w, q1.x, q1.y, q1.z, q1.w};
            s16x8 ah, al;
            #pragma unroll
            for (int j = 0; j < 8; ++j) { ah[j] = (short)(uu[j] & 0xffff); al[j] = (short)(uu[j] >> 16); }
            #pragma unroll
            for (int g = 0; g < 2; ++g) {
                const size_t tb = (((size_t)(nh * 2 + g) * 4 + s) * 64 + lane) * 8;
                const s16x8 bh = *reinterpret_cast<const s16x8*>(wo_h + tb);
                const s16x8 bl = *reinterpret_cast<const s16x8*>(wo_l + tb);
                acc4[g] = MFMA(ah, bh, acc4[g]);
                acc4[g] = MFMA(al, bh, acc4[g]);
                acc4[g] = MFMA(ah, bl, acc4[g]);
            }
        }
        const float T = temp[0];
        #pragma unroll
        for (int g = 0; g < 2; ++g) {
            const int n = nh * 32 + g * 16 + lr;
            const float bv = bo[n];
            #pragma unroll
            for (int j = 0; j < 4; ++j)
                sm.lgt[mt * 16 + ks * 4 + j][n] = (acc4[g][j] + bv) / T;
        }
    }
    __syncthreads();

    // ============ softmax + top-8 + contested detection ============
    {
        const float tau = TAU / temp[0];
        for (int j = 0; j < 8; ++j) {
            const int r = wv * 8 + j;
            const float v = sm.lgt[r][lane];
            float m = v;
            #pragma unroll
            for (int mk = 32; mk >= 1; mk >>= 1) m = fmaxf(m, __shfl_xor(m, mk));
            float p = expf(v - m);
            float ssum = p;
            #pragma unroll
            for (int mk = 32; mk >= 1; mk >>= 1) ssum += __shfl_xor(ssum, mk);
            const float gp = p / ssum;
            out_gp[(size_t)(row_base + r) * 64 + lane] = gp;

            float pv = v;
            int   pi = lane;
            float sum8 = 0.f, myv = 0.f, prev = 0.f;
            int   myi = 0;
            bool  contested = false;
            #pragma unroll
            for (int t = 0; t < 9; ++t) {
                float cv = pv;
                int   ci = pi;
                #pragma unroll
                for (int mk = 32; mk >= 1; mk >>= 1) {
                    const float ov = __shfl_xor(cv, mk);
                    const int   oi = __shfl_xor(ci, mk);
                    if (ov > cv || (ov == cv && oi < ci)) { cv = ov; ci = oi; }
                }
                if (t > 0 && (prev - cv) < tau) contested = true;
                prev = cv;
                if (t < 8) {
                    const float g = __shfl(gp, ci);
                    sum8 += g;
                    if (lane == t)  { myv = g; myi = ci; }
                    if (lane == ci) pv = -3.0e38f;
                }
            }
            if (lane < 8) {
                out_topp[(size_t)(row_base + r) * 8 + lane] = myv / sum8;
                out_topi[(size_t)(row_base + r) * 8 + lane] = (float)myi;
            }
            if (lane == 0 && contested) atomicOr(&cmask, 1u << r);
        }
    }

    // ============ fp64 rescue of contested rows (block-parallel) ============
    __syncthreads();
    unsigned cm = cmask;   // uniform across block
    while (cm) {
        const int r = __ffs(cm) - 1;
        cm &= cm - 1;
        const float* xr = x + (size_t)(row_base + r) * 1024;
        const int c = tid;
        const int wvv = tid >> 6;

        double a0 = 0.0, a1 = 0.0, a2 = 0.0, a3 = 0.0;
        for (int k = 0; k < 1024; k += 4) {
            a0 = fma((double)xr[k + 0], (double)W_in[(size_t)(k + 0) * 256 + c], a0);
            a1 = fma((double)xr[k + 1], (double)W_in[(size_t)(k + 1) * 256 + c], a1);
            a2 = fma((double)xr[k + 2], (double)W_in[(size_t)(k + 2) * 256 + c], a2);
            a3 = fma((double)xr[k + 3], (double)W_in[(size_t)(k + 3) * 256 + c], a3);
        }
        const double h0 = fmax((a0 + a1) + (a2 + a3) + (double)b_in[c], 0.0);

        double s = h0, q = h0 * h0;
        #pragma unroll
        for (int m = 1; m < 64; m <<= 1) { s += __shfl_xor(s, m); q += __shfl_xor(q, m); }
        if (lane == 0) { sm.rred[wvv * 2] = s; sm.rred[wvv * 2 + 1] = q; }
        __syncthreads();
        {
            const double ss = (sm.rred[0] + sm.rred[2]) + (sm.rred[4] + sm.rred[6]);
            const double qq = (sm.rred[1] + sm.rred[3]) + (sm.rred[5] + sm.rred[7]);
            const double mu = ss * (1.0 / 256.0);
            const double rsv = 1.0 / sqrt(qq * (1.0 / 256.0) - mu * mu + 1e-5);
            sm.u.rs.a1d[c] = fmax((h0 - mu) * rsv * (double)ln1_g[c] + (double)ln1_b[c], 0.0);
        }
        __syncthreads();

        double b0 = 0.0, b1c = 0.0, b2c = 0.0, b3c = 0.0;
        for (int k = 0; k < 256; k += 4) {
            b0  = fma(sm.u.rs.a1d[k + 0], (double)W1[(size_t)(k + 0) * 256 + c], b0);
            b1c = fma(sm.u.rs.a1d[k + 1], (double)W1[(size_t)(k + 1) * 256 + c], b1c);
            b2c = fma(sm.u.rs.a1d[k + 2], (double)W1[(size_t)(k + 2) * 256 + c], b2c);
            b3c = fma(sm.u.rs.a1d[k + 3], (double)W1[(size_t)(k + 3) * 256 + c], b3c);
        }
        const double h1 = (b0 + b1c) + (b2c + b3c) + (double)b1[c] + h0;

        s = h1; q = h1 * h1;
        #pragma unroll
        for (int m = 1; m < 64; m <<= 1) { s += __shfl_xor(s, m); q += __shfl_xor(q, m); }
        if (lane == 0) { sm.rred[wvv * 2] = s; sm.rred[wvv * 2 + 1] = q; }
        __syncthreads();   // also orders stage-2 a1d reads before rewrite
        {
            const double ss = (sm.rred[0] + sm.rred[2]) + (sm.rred[4] + sm.rred[6]);
            const double qq = (sm.rred[1] + sm.rred[3]) + (sm.rred[5] + sm.rred[7]);
            const double mu = ss * (1.0 / 256.0);
            const double rsv = 1.0 / sqrt(qq * (1.0 / 256.0) - mu * mu + 1e-5);
            sm.u.rs.a1d[c] = fmax((h1 - mu) * rsv * (double)ln2_g[c] + (double)ln2_b[c], 0.0);
        }
        __syncthreads();

        if (c < 128) {
            double d0 = 0.0, d1 = 0.0, d2 = 0.0, d3 = 0.0;
            for (int k = 0; k < 256; k += 4) {
                d0 = fma(sm.u.rs.a1d[k + 0], (double)W2[(size_t)(k + 0) * 128 + c], d0);
                d1 = fma(sm.u.rs.a1d[k + 1], (double)W2[(size_t)(k + 1) * 128 + c], d1);
                d2 = fma(sm.u.rs.a1d[k + 2], (double)W2[(size_t)(k + 2) * 128 + c], d2);
                d3 = fma(sm.u.rs.a1d[k + 3], (double)W2[(size_t)(k + 3) * 128 + c], d3);
            }
            sm.u.rs.h2d[c] = (d0 + d1) + (d2 + d3) + (double)b2[c];
        }
        __syncthreads();

        if (c < 64) {
            double e0 = 0.0, e1 = 0.0;
            for (int k = 0; k < 128; k += 2) {
                e0 = fma(sm.u.rs.h2d[k + 0], (double)Wo[(size_t)(k + 0) * 64 + c], e0);
                e1 = fma(sm.u.rs.h2d[k + 1], (double)Wo[(size_t)(k + 1) * 64 + c], e1);
            }
            sm.u.rs.lgd[c] = (e0 + e1 + (double)bo[c]) / (double)temp[0];
        }
        __syncthreads();

        if (tid < 64) {
            const int ln = tid;
            const double v = sm.u.rs.lgd[ln];
            double m = v;
            #pragma unroll
            for (int mk = 32; mk >= 1; mk >>= 1) m = fmax(m, __shfl_xor(m, mk));
            const double p = exp(v - m);
            double ssum = p;
            #pragma unroll
            for (int mk = 32; mk >= 1; mk >>= 1) ssum += __shfl_xor(ssum, mk);
            const double gp = p / ssum;
            out_gp[(size_t)(row_base + r) * 64 + ln] = (float)gp;

            double pv = gp;
            int    pi = ln;
            double sum8 = 0.0, myv = 0.0;
            int    myi = 0;
            #pragma unroll
            for (int t = 0; t < 8; ++t) {
                double cv = pv;
                int    ci = pi;
                #pragma unroll
                for (int mk = 32; mk >= 1; mk >>= 1) {
                    const double ov = __shfl_xor(cv, mk);
                    const int    oi = __shfl_xor(ci, mk);
                    if (ov > cv || (ov == cv && oi < ci)) { cv = ov; ci = oi; }
                }
                sum8 += cv;
                if (ln == t)  { myv = cv; myi = ci; }
                if (ln == ci) pv = -1.0;
            }
            if (ln < 8) {
                out_topp[(size_t)(row_base + r) * 8 + ln] = (float)(myv / sum8);
                out_topi[(size_t)(row_base + r) * 8 + ln] = (float)myi;
            }
        }
        __syncthreads();
    }
}

extern "C" void kernel_launch(void* const* d_in, const int* in_sizes, int n_in,
                              void* d_out, int out_size, void* d_ws, size_t ws_size,
                              hipStream_t stream) {
    const float* x     = (const float*)d_in[0];
    const float* W_in  = (const float*)d_in[1];
    const float* b_in  = (const float*)d_in[2];
    const float* ln1_g = (const float*)d_in[3];
    const float* ln1_b = (const float*)d_in[4];
    const float* W1    = (const float*)d_in[5];
    const float* b1    = (const float*)d_in[6];
    const float* ln2_g = (const float*)d_in[7];
    const float* ln2_b = (const float*)d_in[8];
    const float* W2    = (const float*)d_in[9];
    const float* b2    = (const float*)d_in[10];
    const float* Wo    = (const float*)d_in[11];
    const float* bo    = (const float*)d_in[12];
    const float* temp  = (const float*)d_in[13];

    prep_frag<<<dim3(180), dim3(256), 0, stream>>>(W_in, W1, W2, Wo, d_ws);
    gating_mfma<<<dim3(65536 / ROWS), dim3(NTHREADS), 0, stream>>>(
        x, W_in, b_in, ln1_g, ln1_b, W1, b1, ln2_g, ln2_b, W2, b2, Wo, bo, temp,
        d_ws, (float*)d_out);
}